// Round 8
// baseline (176.380 us; speedup 1.0000x reference)
//
#include <hip/hip_runtime.h>
#include <hip/hip_bf16.h>

#define TT 512
#define BB 64
#define HH 512
#define KK 16

typedef __attribute__((ext_vector_type(8))) short bf16x8;
typedef __attribute__((ext_vector_type(4))) short bf16x4;
typedef __attribute__((ext_vector_type(4))) float f32x4;

// v_mfma_f32_16x16x16_bf16 — legacy gfx90a spelling, carried forward on gfx950.
// NOTE: do NOT gate on __has_builtin (false in the host pass); call directly.
#define MFMA_K16(A, B, C) __builtin_amdgcn_mfma_f32_16x16x16bf16_1k(A, B, C, 0, 0, 0)
#define MFMA_K32(A, B, C) __builtin_amdgcn_mfma_f32_16x16x32_bf16(A, B, C, 0, 0, 0)

__device__ __forceinline__ unsigned short f2bf(float f) {
    union { __hip_bfloat16 h; unsigned short u; } cvt;
    cvt.h = __float2bfloat16(f);
    return cvt.u;
}

// branch-free RNE f32->bf16 (inputs are finite non-NaN here)
__device__ __forceinline__ short rne_bf(float x) {
    unsigned u = __float_as_uint(x);
    u += 0x7fffu + ((u >> 16) & 1u);
    return (short)(u >> 16);
}

__device__ __forceinline__ float bf2f(short s) {
    return __uint_as_float(((unsigned)(unsigned short)s) << 16);
}

// ---------------------------------------------------------------------------
// prep: W1 (512x512 f32 [k][n]) -> W1f, FRAGMENT-MAJOR bf16:
//   tile (kt 0..15, gnt 0..31) holds B[k=32kt+8q+i][n=16gnt+nl] at
//   W1f[(kt*32+gnt)*512 + lane*8 + i],  lane = q*16+nl.
// One B-frag load in em = 64 lanes x 16 B contiguous (1 KB coalesced, L2-hot).
// Also W2 -> W2t (bf16 [n][k]) and zero out[0].
// ---------------------------------------------------------------------------
__global__ void prep_kernel(const float* __restrict__ W1, const float* __restrict__ W2,
                            unsigned short* __restrict__ W1f, unsigned short* __restrict__ W2t,
                            float* __restrict__ out) {
    const int bi = blockIdx.x, tx = threadIdx.x;
    if (bi < 64) {
        __shared__ float Ls[64][65];   // Ls[n_local][k_local]
        const int ti = bi & 7, tj = bi >> 3;
        const int r0 = ti * 64, c0 = tj * 64;  // r0: k-range, c0: n-range
        const int r = tx >> 4, c4 = (tx & 15) * 4;
#pragma unroll
        for (int i = 0; i < 4; ++i) {
            float4 v = *(const float4*)(W1 + (size_t)(r0 + r + 16 * i) * HH + c0 + c4);
            Ls[c4 + 0][r + 16 * i] = v.x;
            Ls[c4 + 1][r + 16 * i] = v.y;
            Ls[c4 + 2][r + 16 * i] = v.z;
            Ls[c4 + 3][r + 16 * i] = v.w;
        }
        __syncthreads();
#pragma unroll
        for (int p = 0; p < 2; ++p) {
            const int flat = p * 256 + tx;      // 0..511
            const int tl = flat >> 6;           // tile-local 0..7
            const int lane = flat & 63;
            const int q = lane >> 4, nl = lane & 15;
            const int ktl = tl >> 2, gl = tl & 3;
            const int kt = ti * 2 + ktl;        // 0..15
            const int gnt = tj * 4 + gl;        // 0..31
            const int nloc = 16 * gl + nl, kloc = 32 * ktl + 8 * q;
            bf16x8 o;
#pragma unroll
            for (int i = 0; i < 8; ++i) o[i] = (short)f2bf(Ls[nloc][kloc + i]);
            *(bf16x8*)(W1f + ((size_t)(kt * 32 + gnt) * 64 + lane) * 8) = o;
        }
    } else {
        if (tx == 0) out[0] = 0.0f;
        for (int idx = tx; idx < 16 * HH; idx += 256) {
            const int n = idx >> 9, k = idx & 511;
            W2t[idx] = f2bf(W2[k * KK + n]);
        }
    }
}

// ---------------------------------------------------------------------------
// em = relu(hidden @ W1 + b1) @ W2 + b2.  No LDS / no barriers in the k-loop:
// B-frags load straight from fragment-major W1f (L2-hot, coalesced), A-frags
// straight from hidden (fp32->bf16 in reg).  512 blocks x 128 thr; block =
// 64 rows x 512 cols; wave = 64 rows x 256 cols (acc 4x16 f32x4 = 256 AGPRs,
// 1 wave/SIMD via __launch_bounds__(128,1)).  GEMM2 via Hb LDS round-trip.
// ---------------------------------------------------------------------------
__global__ __launch_bounds__(128, 1)
void em_kernel(const float* __restrict__ hidden, const unsigned short* __restrict__ W1f,
               const float* __restrict__ b1, const unsigned short* __restrict__ W2t,
               const float* __restrict__ b2, float* __restrict__ em) {
    __shared__ unsigned short Hb[64 * 264];   // 33.8 KB

    const int tx = threadIdx.x;
    const int wn = tx >> 6, lane = tx & 63;
    const int q = lane >> 4, nl = lane & 15;
    const int row0 = blockIdx.x * 64;

    f32x4 acc[4][16];
#pragma unroll
    for (int mt = 0; mt < 4; ++mt)
#pragma unroll
        for (int nt = 0; nt < 16; ++nt) acc[mt][nt] = (f32x4){0.f, 0.f, 0.f, 0.f};

    for (int kt = 0; kt < 16; ++kt) {
        // A-frags: A[m=nl][k=8q+j], rows row0+16mt+nl, cols 32kt+8q..+8
        bf16x8 a[4];
#pragma unroll
        for (int mt = 0; mt < 4; ++mt) {
            const float* ap = hidden + (size_t)(row0 + 16 * mt + nl) * HH + kt * 32 + q * 8;
            float4 v0 = *(const float4*)(ap);
            float4 v1 = *(const float4*)(ap + 4);
            bf16x8 o;
            o[0] = (short)f2bf(v0.x); o[1] = (short)f2bf(v0.y);
            o[2] = (short)f2bf(v0.z); o[3] = (short)f2bf(v0.w);
            o[4] = (short)f2bf(v1.x); o[5] = (short)f2bf(v1.y);
            o[6] = (short)f2bf(v1.z); o[7] = (short)f2bf(v1.w);
            a[mt] = o;
        }
        // B-frags: one coalesced 16B/lane load per n-tile
        const bf16x8* bp = (const bf16x8*)W1f + (size_t)(kt * 32 + wn * 16) * 64 + lane;
        bf16x8 b[16];
#pragma unroll
        for (int nt = 0; nt < 16; ++nt) b[nt] = bp[nt * 64];
#pragma unroll
        for (int nt = 0; nt < 16; ++nt)
#pragma unroll
            for (int mt = 0; mt < 4; ++mt)
                acc[mt][nt] = MFMA_K32(a[mt], b[nt], acc[mt][nt]);
    }

    // epilogue: per 256-col chunk, relu(acc+b1) -> Hb (bf16), then GEMM2
    f32x4 acc2[2];
    acc2[0] = (f32x4){0.f, 0.f, 0.f, 0.f};
    acc2[1] = (f32x4){0.f, 0.f, 0.f, 0.f};
    for (int c = 0; c < 2; ++c) {
        __syncthreads();   // previous chunk's GEMM2 readers done
        if (wn == c) {
#pragma unroll
            for (int nt = 0; nt < 16; ++nt) {
                const float bv = b1[c * 256 + 16 * nt + nl];
#pragma unroll
                for (int mt = 0; mt < 4; ++mt) {
#pragma unroll
                    for (int r = 0; r < 4; ++r) {
                        float v = acc[mt][nt][r] + bv;
                        v = v > 0.f ? v : 0.f;
                        Hb[(16 * mt + 4 * q + r) * 264 + nt * 16 + nl] = f2bf(v);
                    }
                }
            }
        }
        __syncthreads();   // Hb ready
#pragma unroll
        for (int ks = 0; ks < 8; ++ks) {
            bf16x8 b2f = *(const bf16x8*)(W2t + nl * HH + c * 256 + ks * 32 + q * 8);
#pragma unroll
            for (int mt2 = 0; mt2 < 2; ++mt2) {
                bf16x8 a2 = *(const bf16x8*)(Hb + (32 * wn + 16 * mt2 + nl) * 264 + ks * 32 + q * 8);
                acc2[mt2] = MFMA_K32(a2, b2f, acc2[mt2]);
            }
        }
    }
#pragma unroll
    for (int mt2 = 0; mt2 < 2; ++mt2)
#pragma unroll
        for (int r = 0; r < 4; ++r) {
            const int row = row0 + 32 * wn + 16 * mt2 + 4 * q + r;
            em[(size_t)row * KK + nl] = acc2[mt2][r] + b2[nl];
        }
}

// ---------------------------------------------------------------------------
// Phase A: chunked matrix-product scan. 1024 waves = 16 chunks x 64 batches
// (256 blocks x 4 waves — full GPU). Each wave: P_c over 32 steps,
// A_t = diag(exp(e_t)) * M (bf16), M = bf16(exp(T)); chunk 0 absorbs t=0 as
// diag(exp(e_0)). D-layout == B-frag layout -> in-lane feedback only.
// Renorm every 4 steps (lagged P[0][0] capture, applied off-chain).
// ---------------------------------------------------------------------------
__global__ void chunk_kernel(const float* __restrict__ em, const float* __restrict__ trans,
                             const int* __restrict__ lens,
                             float* __restrict__ Pfull, float* __restrict__ Cfull,
                             float* __restrict__ Ppart, float* __restrict__ Cpart) {
    const int tx = threadIdx.x;
    const int id = blockIdx.x * 4 + (tx >> 6);   // 0..1023
    const int lane = tx & 63, q = lane >> 4, col = lane & 15;
    const int c = id >> 6, b = id & 63;

    float mf[4];
    {
        float4 tv = *(const float4*)(trans + col * 16 + 4 * q);
        mf[0] = bf2f(rne_bf(__expf(tv.x)));
        mf[1] = bf2f(rne_bf(__expf(tv.y)));
        mf[2] = bf2f(rne_bf(__expf(tv.z)));
        mf[3] = bf2f(rne_bf(__expf(tv.w)));
    }
    const int Lm1 = lens[b] - 1;
    const int tb0 = 32 * c;

    float ebuf[8];
#pragma unroll
    for (int i = 0; i < 8; ++i)
        ebuf[i] = em[(size_t)((tb0 + i) * BB + b) * KK + col];

    bf16x4 gb;
#pragma unroll
    for (int i = 0; i < 4; ++i)
        gb[i] = (4 * q + i == col) ? rne_bf(1.0f) : (short)0;

    const f32x4 zc = (f32x4){0.f, 0.f, 0.f, 0.f};
    f32x4 d = (f32x4){0.f, 0.f, 0.f, 0.f};
    float K = 1.0f, rk = 1.0f, lk = 0.0f, Cacc = 0.0f;

    for (int sb = 0; sb < 32; sb += 8) {
        const bool refill = (sb < 24);
#pragma unroll
        for (int s8 = 0; s8 < 8; ++s8) {
            const int t = tb0 + sb + s8;
            const float eraw = ebuf[s8];
            if (refill)
                ebuf[s8] = em[(size_t)((t + 8) * BB + b) * KK + col];
            float ev = __expf(eraw);
            if ((s8 & 3) == 0 && (sb + s8) >= 4) {  // lagged renorm (off-chain)
                ev *= rk;
                Cacc += lk;
            }
            bf16x4 af;
            af[0] = rne_bf(ev * mf[0]); af[1] = rne_bf(ev * mf[1]);
            af[2] = rne_bf(ev * mf[2]); af[3] = rne_bf(ev * mf[3]);
            if (sb == 0 && s8 == 0 && c == 0) {  // t=0: A_0 = diag(exp(e_0))
#pragma unroll
                for (int i = 0; i < 4; ++i)
                    af[i] = (4 * q + i == col) ? rne_bf(ev) : (short)0;
            }
            d = MFMA_K16(af, gb, zc);
            if ((s8 & 3) == 1) {  // lagged capture of P[0][0]
                K = __shfl(d[0], 0, 64);
                const float Km = fmaxf(K, 1e-30f);
                rk = 1.0f / Km;
                lk = __logf(Km);
            }
            if (t == Lm1) {
#pragma unroll
                for (int r = 0; r < 4; ++r)
                    Ppart[b * 256 + (4 * q + r) * 16 + col] = d[r];
                if (lane == 0) Cpart[b] = Cacc;
            }
            gb[0] = rne_bf(d[0]); gb[1] = rne_bf(d[1]);
            gb[2] = rne_bf(d[2]); gb[3] = rne_bf(d[3]);
        }
    }
#pragma unroll
    for (int r = 0; r < 4; ++r)
        Pfull[(size_t)(b * 16 + c) * 256 + (4 * q + r) * 16 + col] = d[r];
    if (lane == 0) Cfull[b * 16 + c] = Cacc;
}

// ---------------------------------------------------------------------------
// Phase B + gold, fused. One block per batch (64 x 256 thr).
// gold: gather-sum over t (all threads); combine: ones-vector through the
// chunk products (wave 0).  atomicAdd(out, fwd - gold).
// gold uses log(bf16(exp(T))) so the scan's M-quantization cancels.
// ---------------------------------------------------------------------------
__global__ void combine_kernel(const float* __restrict__ em, const float* __restrict__ trans,
                               const int* __restrict__ lens, const int* __restrict__ tags,
                               const float* __restrict__ Pfull, const float* __restrict__ Cfull,
                               const float* __restrict__ Ppart, const float* __restrict__ Cpart,
                               float* __restrict__ out) {
    __shared__ float trs[256];
    __shared__ float red[4];
    const int b = blockIdx.x, tid = threadIdx.x;
    trs[tid] = __logf(bf2f(rne_bf(__expf(trans[tid]))));
    __syncthreads();
    const int L = lens[b];
    float v = 0.0f;
#pragma unroll
    for (int p = 0; p < 2; ++p) {
        const int t = p * 256 + tid;
        if (t < L) {
            const int tg = tags[t * BB + b];
            float u = em[((size_t)t * BB + b) * KK + tg];
            if (t > 0) u += trs[tg * 16 + tags[(t - 1) * BB + b]];
            v += u;
        }
    }
#pragma unroll
    for (int dd = 1; dd < 64; dd <<= 1) v += __shfl_xor(v, dd, 64);
    if ((tid & 63) == 0) red[tid >> 6] = v;
    __syncthreads();

    if (tid < 64) {
        const int j = tid & 15;   // 4 replica groups compute identically
        const int base = (tid >> 4) << 4;
        const int cstar = (lens[b] - 1) >> 5;
        float g = 1.0f, acc = 0.0f;
        for (int c = 0; c < 16; ++c) {
            const bool act = (c <= cstar);
            const float* P = (c < cstar) ? (Pfull + (size_t)(b * 16 + c) * 256)
                                         : (Ppart + b * 256);
            float gn = 0.0f;
#pragma unroll
            for (int k = 0; k < 16; ++k) {
                const float gk = __shfl(g, base + k, 64);
                gn += P[j * 16 + k] * gk;
            }
            if (act) {
                float m = gn;
#pragma unroll
                for (int dd = 1; dd < 16; dd <<= 1) m = fmaxf(m, __shfl_xor(m, dd, 64));
                g = gn / m;
                acc += __logf(m) + ((c < cstar) ? Cfull[b * 16 + c] : Cpart[b]);
            }
        }
        float ssum = g;
#pragma unroll
        for (int dd = 1; dd < 16; dd <<= 1) ssum += __shfl_xor(ssum, dd, 64);
        const float fwd = acc + __logf(ssum);
        if (tid == 0)
            atomicAdd(out, fwd - (red[0] + red[1] + red[2] + red[3]));
    }
}

extern "C" void kernel_launch(void* const* d_in, const int* in_sizes, int n_in,
                              void* d_out, int out_size, void* d_ws, size_t ws_size,
                              hipStream_t stream) {
    const float* hidden = (const float*)d_in[0];
    const float* W1     = (const float*)d_in[1];
    const float* b1     = (const float*)d_in[2];
    const float* W2     = (const float*)d_in[3];
    const float* b2     = (const float*)d_in[4];
    const float* trans  = (const float*)d_in[5];
    const int*   lens   = (const int*)d_in[6];
    const int*   tags   = (const int*)d_in[7];
    float* out = (float*)d_out;

    char* ws = (char*)d_ws;
    float* em = (float*)ws;                                   // [0, 2 MB)
    unsigned short* W1f = (unsigned short*)(ws + 2097152);    // 512 KB (dead after em)
    unsigned short* W2t = (unsigned short*)(ws + 2621440);    // 16 KB  (dead after em)
    float* Pfull = (float*)(ws + 2097152);                    // 1 MB, ALIASES W1f/W2t (chunk runs after em)
    float* Cfull = (float*)(ws + 3145728);                    // 4 KB
    float* Ppart = (float*)(ws + 3149824);                    // 64 KB
    float* Cpart = (float*)(ws + 3215360);                    // 256 B

    prep_kernel<<<65, 256, 0, stream>>>(W1, W2, W1f, W2t, out);
    em_kernel<<<512, 128, 0, stream>>>(hidden, W1f, b1, W2t, b2, em);
    chunk_kernel<<<256, 256, 0, stream>>>(em, trans, lens, Pfull, Cfull, Ppart, Cpart);
    combine_kernel<<<64, 256, 0, stream>>>(em, trans, lens, tags, Pfull, Cfull, Ppart, Cpart, out);
}